// Round 1
// baseline (11000.708 us; speedup 1.0000x reference)
//
#include <hip/hip_runtime.h>
#include <cstddef>

// Problem constants (fixed by the reference)
#define TT    256
#define NROW  2048
#define GBN   5
#define EDG   65536

// ---------------- workspace float offsets ----------------
enum : int {
  P_WIH0T = 0,            // [5][512]
  P_WHH0T = 2560,         // packed4 [32][512] float4
  P_WIH1T = 68096,        // packed4 [32][512]
  P_WHH1T = 133632,       // packed4 [32][512]
  P_B0    = 199168,       // 512
  P_B1    = 199680,       // 512
  AP_W1T  = 200192,       // packed4 [32][128]
  T_WIH0T = 216576,
  T_WHH0T = 219136,
  T_WIH1T = 284672,
  T_WHH1T = 350208,
  T_B0    = 415744,
  T_B1    = 416256,
  AT_W1T  = 416768,
  XBUF    = 433152,       // [2048][128]
  GBUFO   = 695296,       // [5][128]
  DINVP   = 695936,       // 2048
  DINVT   = 697984,       // 2048
  H16     = 700032,       // [2048][16]
  PG1     = 732800,       // [2048][16]
  H128    = 765568,       // [2048][128]
  PGB     = 1027712,      // [2048][128]
  TG1     = 1289856,      // [2048][16]  (unused slack ok)
  TGB     = 1322624,      // [2048][128]
  WS_END  = 1584768
};

__device__ __forceinline__ float sigf(float x) { return 1.0f / (1.0f + __expf(-x)); }
__device__ __forceinline__ float tanh_fast(float x) { return 2.0f * sigf(2.0f * x) - 1.0f; }

// ---------------- prep kernels ----------------
// pack W [C][K] row-major -> dst float4[kc*C + j] = W[j][4kc..4kc+3]
__global__ void k_pack4c(const float* __restrict__ W, float* __restrict__ dst,
                         int K, int C, int n) {
  int i = blockIdx.x * blockDim.x + threadIdx.x;
  if (i >= n) return;
  int kc = i / C, j = i % C;
  const float* s = W + (size_t)j * K + kc * 4;
  float4 v = make_float4(s[0], s[1], s[2], s[3]);
  ((float4*)dst)[i] = v;
}

// plain transpose: dst[k*C + j] = W[j*K + k]
__global__ void k_t(const float* __restrict__ W, float* __restrict__ dst,
                    int K, int C, int n) {
  int i = blockIdx.x * blockDim.x + threadIdx.x;
  if (i >= n) return;
  int k = i / C, j = i % C;
  dst[i] = W[(size_t)j * K + k];
}

__global__ void k_badd(const float* __restrict__ a, const float* __restrict__ b,
                       float* __restrict__ d, int n) {
  int i = blockIdx.x * blockDim.x + threadIdx.x;
  if (i < n) d[i] = a[i] + b[i];
}

__global__ void k_zero(float* __restrict__ p, int n) {
  int i = blockIdx.x * blockDim.x + threadIdx.x;
  if (i < n) p[i] = 0.0f;
}

__global__ void k_fill1(float* __restrict__ p, int n) {
  int i = blockIdx.x * blockDim.x + threadIdx.x;
  if (i < n) p[i] = 1.0f;
}

__global__ void k_deg(const int* __restrict__ col, const float* __restrict__ w,
                      float* __restrict__ deg, int n) {
  int i = blockIdx.x * blockDim.x + threadIdx.x;
  if (i < n) atomicAdd(&deg[col[i]], w[i]);
}

__global__ void k_dinv(float* __restrict__ deg, int n) {
  int i = blockIdx.x * blockDim.x + threadIdx.x;
  if (i < n) deg[i] = rsqrtf(deg[i]);   // deg >= 1 always (self loop)
}

// ---------------- fused 2-layer LSTM + online prefix-softmax attention ----------------
// Each block owns R rows (price: 8 rows, 256 blocks; trend: 5 rows, 1 block) and runs
// all 256 timesteps locally. Attention state (m, den, num[128], acc[128]) lives in
// registers, wave w = row w.
__global__ __launch_bounds__(512) void k_lstm_attn(
    const float* __restrict__ price, const float* __restrict__ gtrend,
    float* __restrict__ ws,
    const float* __restrict__ apB1, const float* __restrict__ apW2, const float* __restrict__ apB2,
    const float* __restrict__ atB1, const float* __restrict__ atW2, const float* __restrict__ atB2,
    int nPrice)
{
  const int tid = threadIdx.x;
  const bool isP = ((int)blockIdx.x) < nPrice;
  const int R = isP ? 8 : 5;
  const float* seq = isP ? (price + (size_t)blockIdx.x * 8 * (TT * 5)) : gtrend;
  const float* wih0t = ws + (isP ? P_WIH0T : T_WIH0T);
  const float* whh0t = ws + (isP ? P_WHH0T : T_WHH0T);
  const float* wih1t = ws + (isP ? P_WIH1T : T_WIH1T);
  const float* whh1t = ws + (isP ? P_WHH1T : T_WHH1T);
  const float* b0   = ws + (isP ? P_B0 : T_B0);
  const float* b1   = ws + (isP ? P_B1 : T_B1);
  const float* w1t  = ws + (isP ? AP_W1T : AT_W1T);
  const float* b1a  = isP ? apB1 : atB1;
  const float* w2   = isP ? apW2 : atW2;
  const float  b2v  = isP ? apB2[0] : atB2[0];
  float* out = ws + (isP ? (XBUF + (size_t)blockIdx.x * 8 * 128) : GBUFO);

  __shared__ float h0s[8][128], c0s[8][128], h1s[8][128], c1s[8][128];
  __shared__ float gbuf[8][512];
  __shared__ float xts[8][5];

  for (int i = tid; i < 8 * 128; i += 512) {
    h0s[0][i] = 0.0f; c0s[0][i] = 0.0f; h1s[0][i] = 0.0f; c1s[0][i] = 0.0f;
  }
  if (tid < 40) xts[tid / 5][tid % 5] = 0.0f;
  __syncthreads();

  const int wv = tid >> 6, ln = tid & 63;
  float num0 = 0.f, num1 = 0.f, acc0 = 0.f, acc1 = 0.f;
  float mrun = -1e30f, den = 0.f;
  const int j = tid;

  for (int t = 0; t < TT; ++t) {
    // stage x_t
    if (tid < R * 5) {
      int r = tid / 5, k = tid % 5;
      xts[r][k] = seq[(size_t)r * (TT * 5) + t * 5 + k];
    }
    __syncthreads();   // S1: xt ready; prior-iter gbuf reads done

    // ---- gates0 = x_t @ Wih0.T + h0 @ Whh0.T + b0 ----
    {
      float acc[8];
      float bb = b0[j];
      #pragma unroll
      for (int r = 0; r < 8; ++r) acc[r] = bb;
      #pragma unroll
      for (int k = 0; k < 5; ++k) {
        float w = wih0t[k * 512 + j];
        #pragma unroll
        for (int r = 0; r < 8; ++r) acc[r] = fmaf(xts[r][k], w, acc[r]);
      }
      const float4* wp = (const float4*)whh0t;
      #pragma unroll 4
      for (int kc = 0; kc < 32; ++kc) {
        float4 w4 = wp[kc * 512 + j];
        #pragma unroll
        for (int r = 0; r < 8; ++r) {
          float4 h4 = ((const float4*)h0s)[r * 32 + kc];
          acc[r] = fmaf(h4.x, w4.x, fmaf(h4.y, w4.y, fmaf(h4.z, w4.z, fmaf(h4.w, w4.w, acc[r]))));
        }
      }
      #pragma unroll
      for (int r = 0; r < 8; ++r) gbuf[r][j] = acc[r];
    }
    __syncthreads();   // S2

    // ---- h0/c0 update ----
    for (int e = tid; e < 1024; e += 512) {
      int r = e >> 7, cl = e & 127;
      if (r < R) {
        float gi = gbuf[r][cl], gf = gbuf[r][cl + 128];
        float gg = gbuf[r][cl + 256], go = gbuf[r][cl + 384];
        float c = sigf(gf) * c0s[r][cl] + sigf(gi) * tanh_fast(gg);
        c0s[r][cl] = c;
        h0s[r][cl] = sigf(go) * tanh_fast(c);
      }
    }
    __syncthreads();   // S3

    // ---- gates1 = h0_new @ Wih1.T + h1 @ Whh1.T + b1 ----
    {
      float acc[8];
      float bb = b1[j];
      #pragma unroll
      for (int r = 0; r < 8; ++r) acc[r] = bb;
      const float4* wpi = (const float4*)wih1t;
      #pragma unroll 4
      for (int kc = 0; kc < 32; ++kc) {
        float4 w4 = wpi[kc * 512 + j];
        #pragma unroll
        for (int r = 0; r < 8; ++r) {
          float4 h4 = ((const float4*)h0s)[r * 32 + kc];
          acc[r] = fmaf(h4.x, w4.x, fmaf(h4.y, w4.y, fmaf(h4.z, w4.z, fmaf(h4.w, w4.w, acc[r]))));
        }
      }
      const float4* wph = (const float4*)whh1t;
      #pragma unroll 4
      for (int kc = 0; kc < 32; ++kc) {
        float4 w4 = wph[kc * 512 + j];
        #pragma unroll
        for (int r = 0; r < 8; ++r) {
          float4 h4 = ((const float4*)h1s)[r * 32 + kc];
          acc[r] = fmaf(h4.x, w4.x, fmaf(h4.y, w4.y, fmaf(h4.z, w4.z, fmaf(h4.w, w4.w, acc[r]))));
        }
      }
      #pragma unroll
      for (int r = 0; r < 8; ++r) gbuf[r][j] = acc[r];
    }
    __syncthreads();   // S4

    // ---- h1/c1 update ----
    for (int e = tid; e < 1024; e += 512) {
      int r = e >> 7, cl = e & 127;
      if (r < R) {
        float gi = gbuf[r][cl], gf = gbuf[r][cl + 128];
        float gg = gbuf[r][cl + 256], go = gbuf[r][cl + 384];
        float c = sigf(gf) * c1s[r][cl] + sigf(gi) * tanh_fast(gg);
        c1s[r][cl] = c;
        h1s[r][cl] = sigf(go) * tanh_fast(c);
      }
    }
    __syncthreads();   // S5

    // ---- attention scores: a = tanh(h1 @ W1.T + b1a), into gbuf[r][0..127] ----
    for (int e = tid; e < 1024; e += 512) {
      int r = e >> 7, cl = e & 127;
      float a = b1a[cl];
      const float4* wp1 = (const float4*)w1t;
      #pragma unroll 4
      for (int kc = 0; kc < 32; ++kc) {
        float4 w4 = wp1[kc * 128 + cl];
        float4 h4 = ((const float4*)h1s)[r * 32 + kc];
        a = fmaf(h4.x, w4.x, fmaf(h4.y, w4.y, fmaf(h4.z, w4.z, fmaf(h4.w, w4.w, a))));
      }
      gbuf[r][cl] = tanh_fast(a);
    }
    __syncthreads();   // S6

    // ---- s = a @ W2 + b2 (wave wv reduces row wv), then online prefix-softmax ----
    float p = gbuf[wv][ln] * w2[ln] + gbuf[wv][ln + 64] * w2[ln + 64];
    #pragma unroll
    for (int o = 32; o > 0; o >>= 1) p += __shfl_down(p, o);
    float s = __shfl(p, 0) + b2v;

    float nm = fmaxf(mrun, s);
    float e = __expf(s - nm);
    float sc = __expf(mrun - nm);
    den = den * sc + e;
    mrun = nm;
    num0 = num0 * sc + e * h1s[wv][ln];
    num1 = num1 * sc + e * h1s[wv][ln + 64];
    acc0 += num0 / den;
    acc1 += num1 / den;
    // next-iter S1 guarantees gbuf reads above complete before overwrite
  }

  if (wv < R) {
    out[(size_t)wv * 128 + ln] = acc0;
    out[(size_t)wv * 128 + 64 + ln] = acc1;
  }
}

// ---------------- GCN kernels ----------------
// h[r][m] = dot(x[r][:K], W[m][:K])
__global__ void k_lin(const float* __restrict__ x, const float* __restrict__ W,
                      float* __restrict__ h, int M, int K, int n) {
  int i = blockIdx.x * blockDim.x + threadIdx.x;
  if (i >= n) return;
  int r = i / M, m = i % M;
  const float* xr = x + (size_t)r * K;
  const float* wm = W + (size_t)m * K;
  float a = 0.f;
  for (int k = 0; k < K; ++k) a = fmaf(xr[k], wm[k], a);
  h[i] = a;
}

__global__ void k_scatter(const int* __restrict__ rowi, const int* __restrict__ coli,
                          const float* __restrict__ w, const float* __restrict__ dinv,
                          const float* __restrict__ h, float* __restrict__ outp,
                          int M, long long n) {
  long long i = (long long)blockIdx.x * blockDim.x + threadIdx.x;
  if (i >= n) return;
  int e = (int)(i / M), f = (int)(i % M);
  int rs = rowi[e], cd = coli[e];
  float nrm = dinv[rs] * w[e] * dinv[cd];
  atomicAdd(&outp[(size_t)cd * M + f], nrm * h[(size_t)rs * M + f]);
}

// io[v][f] += dinv[v]^2 * h[v][f] + b[f]   (self loop, weight 1, + bias)
__global__ void k_gcn_fin(float* __restrict__ io, const float* __restrict__ h,
                          const float* __restrict__ dinv, const float* __restrict__ b,
                          int M, int n) {
  int i = blockIdx.x * blockDim.x + threadIdx.x;
  if (i >= n) return;
  int v = i / M, f = i % M;
  float dv = dinv[v];
  io[i] += dv * dv * h[i] + b[f];
}

// ---------------- final head: trend = tg@g.T ; out = sigmoid([pg|trend]@mlpW.T + b) ----------------
__global__ __launch_bounds__(256) void k_final(const float* __restrict__ pg, const float* __restrict__ tg,
                                               const float* __restrict__ g, const float* __restrict__ mw,
                                               const float* __restrict__ mb, float* __restrict__ outp) {
  int wv = threadIdx.x >> 6, ln = threadIdx.x & 63;
  int r = blockIdx.x * 4 + wv;
  const float* pr = pg + (size_t)r * 128;
  const float* tr = tg + (size_t)r * 128;
  float pa = pr[ln] * mw[ln] + pr[ln + 64] * mw[ln + 64];
  float t0 = tr[ln], t1 = tr[ln + 64];
  float s[GBN];
  #pragma unroll
  for (int gb = 0; gb < GBN; ++gb)
    s[gb] = g[gb * 128 + ln] * t0 + g[gb * 128 + 64 + ln] * t1;
  #pragma unroll
  for (int o = 32; o > 0; o >>= 1) {
    pa += __shfl_down(pa, o);
    #pragma unroll
    for (int gb = 0; gb < GBN; ++gb) s[gb] += __shfl_down(s[gb], o);
  }
  if (ln == 0) {
    float lg = pa + mb[0];
    #pragma unroll
    for (int gb = 0; gb < GBN; ++gb) lg = fmaf(s[gb], mw[128 + gb], lg);
    outp[r] = 1.0f / (1.0f + __expf(-lg));
  }
}

// ---------------- host launch ----------------
static inline int gdiv(long long n) { return (int)((n + 255) / 256); }

extern "C" void kernel_launch(void* const* d_in, const int* in_sizes, int n_in,
                              void* d_out, int out_size, void* d_ws, size_t ws_size,
                              hipStream_t stream) {
  const float* price  = (const float*)d_in[0];
  const float* gtrend = (const float*)d_in[1];
  const int*   p_ei   = (const int*)d_in[2];
  const float* p_w    = (const float*)d_in[3];
  const int*   t_ei   = (const int*)d_in[4];
  const float* t_w    = (const float*)d_in[5];
  const float* lpWih0 = (const float*)d_in[6];
  const float* lpWhh0 = (const float*)d_in[7];
  const float* lpBih0 = (const float*)d_in[8];
  const float* lpBhh0 = (const float*)d_in[9];
  const float* lpWih1 = (const float*)d_in[10];
  const float* lpWhh1 = (const float*)d_in[11];
  const float* lpBih1 = (const float*)d_in[12];
  const float* lpBhh1 = (const float*)d_in[13];
  const float* ltWih0 = (const float*)d_in[14];
  const float* ltWhh0 = (const float*)d_in[15];
  const float* ltBih0 = (const float*)d_in[16];
  const float* ltBhh0 = (const float*)d_in[17];
  const float* ltWih1 = (const float*)d_in[18];
  const float* ltWhh1 = (const float*)d_in[19];
  const float* ltBih1 = (const float*)d_in[20];
  const float* ltBhh1 = (const float*)d_in[21];
  const float* apW1 = (const float*)d_in[22];
  const float* apB1 = (const float*)d_in[23];
  const float* apW2 = (const float*)d_in[24];
  const float* apB2 = (const float*)d_in[25];
  const float* atW1 = (const float*)d_in[26];
  const float* atB1 = (const float*)d_in[27];
  const float* atW2 = (const float*)d_in[28];
  const float* atB2 = (const float*)d_in[29];
  const float* gp1W = (const float*)d_in[30];
  const float* gp1b = (const float*)d_in[31];
  const float* gp2W = (const float*)d_in[32];
  const float* gp2b = (const float*)d_in[33];
  const float* gt1W = (const float*)d_in[34];
  const float* gt1b = (const float*)d_in[35];
  const float* gt2W = (const float*)d_in[36];
  const float* gt2b = (const float*)d_in[37];
  const float* mlpW = (const float*)d_in[38];
  const float* mlpb = (const float*)d_in[39];

  float* ws = (float*)d_ws;
  float* outp = (float*)d_out;
  if (ws_size < (size_t)WS_END * sizeof(float)) return;

  // --- weight packing ---
  k_pack4c<<<gdiv(16384), 256, 0, stream>>>(lpWhh0, ws + P_WHH0T, 128, 512, 16384);
  k_pack4c<<<gdiv(16384), 256, 0, stream>>>(lpWih1, ws + P_WIH1T, 128, 512, 16384);
  k_pack4c<<<gdiv(16384), 256, 0, stream>>>(lpWhh1, ws + P_WHH1T, 128, 512, 16384);
  k_t<<<gdiv(2560), 256, 0, stream>>>(lpWih0, ws + P_WIH0T, 5, 512, 2560);
  k_badd<<<gdiv(512), 256, 0, stream>>>(lpBih0, lpBhh0, ws + P_B0, 512);
  k_badd<<<gdiv(512), 256, 0, stream>>>(lpBih1, lpBhh1, ws + P_B1, 512);
  k_pack4c<<<gdiv(4096), 256, 0, stream>>>(apW1, ws + AP_W1T, 128, 128, 4096);

  k_pack4c<<<gdiv(16384), 256, 0, stream>>>(ltWhh0, ws + T_WHH0T, 128, 512, 16384);
  k_pack4c<<<gdiv(16384), 256, 0, stream>>>(ltWih1, ws + T_WIH1T, 128, 512, 16384);
  k_pack4c<<<gdiv(16384), 256, 0, stream>>>(ltWhh1, ws + T_WHH1T, 128, 512, 16384);
  k_t<<<gdiv(2560), 256, 0, stream>>>(ltWih0, ws + T_WIH0T, 5, 512, 2560);
  k_badd<<<gdiv(512), 256, 0, stream>>>(ltBih0, ltBhh0, ws + T_B0, 512);
  k_badd<<<gdiv(512), 256, 0, stream>>>(ltBih1, ltBhh1, ws + T_B1, 512);
  k_pack4c<<<gdiv(4096), 256, 0, stream>>>(atW1, ws + AT_W1T, 128, 128, 4096);

  // --- graph degrees -> dinv ---
  k_fill1<<<gdiv(NROW), 256, 0, stream>>>(ws + DINVP, NROW);
  k_deg<<<gdiv(EDG), 256, 0, stream>>>(p_ei + EDG, p_w, ws + DINVP, EDG);
  k_dinv<<<gdiv(NROW), 256, 0, stream>>>(ws + DINVP, NROW);
  k_fill1<<<gdiv(NROW), 256, 0, stream>>>(ws + DINVT, NROW);
  k_deg<<<gdiv(EDG), 256, 0, stream>>>(t_ei + EDG, t_w, ws + DINVT, EDG);
  k_dinv<<<gdiv(NROW), 256, 0, stream>>>(ws + DINVT, NROW);

  // --- fused LSTM x2 + attention (price: 256 blocks x 8 rows; trend: 1 block) ---
  k_lstm_attn<<<257, 512, 0, stream>>>(price, gtrend, ws,
                                       apB1, apW2, apB2, atB1, atW2, atB2, 256);

  // --- price graph: conv1 (128->16) ---
  k_lin<<<gdiv(NROW * 16), 256, 0, stream>>>(ws + XBUF, gp1W, ws + H16, 16, 128, NROW * 16);
  k_zero<<<gdiv(NROW * 16), 256, 0, stream>>>(ws + PG1, NROW * 16);
  k_scatter<<<gdiv((long long)EDG * 16), 256, 0, stream>>>(p_ei, p_ei + EDG, p_w, ws + DINVP,
                                                           ws + H16, ws + PG1, 16, (long long)EDG * 16);
  k_gcn_fin<<<gdiv(NROW * 16), 256, 0, stream>>>(ws + PG1, ws + H16, ws + DINVP, gp1b, 16, NROW * 16);
  // --- price graph: conv2 (16->128) ---
  k_lin<<<gdiv(NROW * 128), 256, 0, stream>>>(ws + PG1, gp2W, ws + H128, 128, 16, NROW * 128);
  k_zero<<<gdiv(NROW * 128), 256, 0, stream>>>(ws + PGB, NROW * 128);
  k_scatter<<<gdiv((long long)EDG * 128), 256, 0, stream>>>(p_ei, p_ei + EDG, p_w, ws + DINVP,
                                                            ws + H128, ws + PGB, 128, (long long)EDG * 128);
  k_gcn_fin<<<gdiv(NROW * 128), 256, 0, stream>>>(ws + PGB, ws + H128, ws + DINVP, gp2b, 128, NROW * 128);

  // --- trend graph: conv1 (input is x!) ---
  k_lin<<<gdiv(NROW * 16), 256, 0, stream>>>(ws + XBUF, gt1W, ws + H16, 16, 128, NROW * 16);
  k_zero<<<gdiv(NROW * 16), 256, 0, stream>>>(ws + TG1, NROW * 16);
  k_scatter<<<gdiv((long long)EDG * 16), 256, 0, stream>>>(t_ei, t_ei + EDG, t_w, ws + DINVT,
                                                           ws + H16, ws + TG1, 16, (long long)EDG * 16);
  k_gcn_fin<<<gdiv(NROW * 16), 256, 0, stream>>>(ws + TG1, ws + H16, ws + DINVT, gt1b, 16, NROW * 16);
  // --- trend graph: conv2 ---
  k_lin<<<gdiv(NROW * 128), 256, 0, stream>>>(ws + TG1, gt2W, ws + H128, 128, 16, NROW * 128);
  k_zero<<<gdiv(NROW * 128), 256, 0, stream>>>(ws + TGB, NROW * 128);
  k_scatter<<<gdiv((long long)EDG * 128), 256, 0, stream>>>(t_ei, t_ei + EDG, t_w, ws + DINVT,
                                                            ws + H128, ws + TGB, 128, (long long)EDG * 128);
  k_gcn_fin<<<gdiv(NROW * 128), 256, 0, stream>>>(ws + TGB, ws + H128, ws + DINVT, gt2b, 128, NROW * 128);

  // --- head ---
  k_final<<<512, 256, 0, stream>>>(ws + PGB, ws + TGB, ws + GBUFO, mlpW, mlpb, outp);
}